// Round 1
// baseline (1505.890 us; speedup 1.0000x reference)
//
#include <hip/hip_runtime.h>
#include <math.h>

// ---------------------------------------------------------------------------
// GAT pipeline: 3x (GEMM -> alpha -> CSR segment-softmax aggregate) + FC
// CSR built per launch (same work every call; graph-capture safe).
// ---------------------------------------------------------------------------

__global__ void count_kernel(const int* __restrict__ ei, int E, int N,
                             int* __restrict__ cnt) {
    int e = blockIdx.x * blockDim.x + threadIdx.x;
    int Etot = E + N;
    if (e >= Etot) return;
    int dst = (e < E) ? ei[E + e] : (e - E);   // self-loops appended
    atomicAdd(&cnt[dst], 1);
}

__global__ __launch_bounds__(1024) void scan_kernel(const int* __restrict__ cnt,
                                                    int N, int Etot,
                                                    int* __restrict__ row_ptr,
                                                    int* __restrict__ cursor) {
    __shared__ int sums[1024];
    int tid = threadIdx.x;
    int chunk = (N + 1023) >> 10;
    int lo = tid * chunk;
    int hi = lo + chunk; if (hi > N) hi = N; if (lo > N) lo = N;
    int s = 0;
    for (int i = lo; i < hi; ++i) s += cnt[i];
    sums[tid] = s;
    __syncthreads();
    for (int off = 1; off < 1024; off <<= 1) {
        int t = (tid >= off) ? sums[tid - off] : 0;
        __syncthreads();
        sums[tid] += t;
        __syncthreads();
    }
    int run = sums[tid] - s;   // exclusive base for this thread's chunk
    for (int i = lo; i < hi; ++i) {
        row_ptr[i] = run;
        cursor[i]  = run;
        run += cnt[i];
    }
    if (tid == 0) row_ptr[N] = Etot;
}

__global__ void scatter_kernel(const int* __restrict__ ei, int E, int N,
                               int* __restrict__ cursor, int* __restrict__ csr_src) {
    int e = blockIdx.x * blockDim.x + threadIdx.x;
    int Etot = E + N;
    if (e >= Etot) return;
    int src, dst;
    if (e < E) { src = ei[e]; dst = ei[E + e]; }
    else       { src = e - E; dst = e - E; }
    int pos = atomicAdd(&cursor[dst], 1);
    csr_src[pos] = src;
}

// ---------------------------------------------------------------------------
// GEMM: out[n, cb+m] = sum_k in[n,k] * W[k, cb+m], m in [0,CHUNK)
// One wave per node, lane covers CHUNK/64 columns. W chunk staged in LDS.
// K, CHUNK compile-time; K*CHUNK must be <= 8192 (32 KB LDS).
// ---------------------------------------------------------------------------
template <int K, int CHUNK>
__global__ __launch_bounds__(256) void gemm_kernel(const float* __restrict__ in,
                                                   const float* __restrict__ W,
                                                   const float* __restrict__ bias,
                                                   float* __restrict__ out,
                                                   int N, int M, int relu) {
    constexpr int PL = CHUNK / 64;
    __shared__ float wlds[K * CHUNK];
    const int cb = blockIdx.y * CHUNK;
    for (int idx = threadIdx.x; idx < K * CHUNK; idx += 256) {
        int k = idx / CHUNK, c = idx % CHUNK;
        wlds[idx] = W[k * M + cb + c];
    }
    __syncthreads();

    const int wid  = threadIdx.x >> 6;
    const int lane = threadIdx.x & 63;
    float b[PL];
#pragma unroll
    for (int j = 0; j < PL; ++j)
        b[j] = bias ? bias[cb + lane + 64 * j] : 0.0f;

    for (int n = blockIdx.x * 4 + wid; n < N; n += gridDim.x * 4) {
        const float* xr = in + (size_t)n * K;
        float acc[PL];
#pragma unroll
        for (int j = 0; j < PL; ++j) acc[j] = 0.0f;
#pragma unroll 4
        for (int k4 = 0; k4 < K / 4; ++k4) {
            float4 xv = ((const float4*)xr)[k4];
            int kb = k4 * 4;
#pragma unroll
            for (int j = 0; j < PL; ++j) {
                acc[j] += xv.x * wlds[(kb + 0) * CHUNK + lane + 64 * j];
                acc[j] += xv.y * wlds[(kb + 1) * CHUNK + lane + 64 * j];
                acc[j] += xv.z * wlds[(kb + 2) * CHUNK + lane + 64 * j];
                acc[j] += xv.w * wlds[(kb + 3) * CHUNK + lane + 64 * j];
            }
        }
#pragma unroll
        for (int j = 0; j < PL; ++j) {
            float v = acc[j] + b[j];
            if (relu) v = fmaxf(v, 0.0f);
            out[(size_t)n * M + cb + lane + 64 * j] = v;
        }
    }
}

// alpha_s[n,h] = sum_c h[n,h,c]*a_src[h,c]; alpha_d likewise. 1 thread/(n,h).
__global__ void alpha_kernel(const float* __restrict__ h,
                             const float* __restrict__ a_src,
                             const float* __restrict__ a_dst,
                             float* __restrict__ alpha_s,
                             float* __restrict__ alpha_d,
                             int N, int H, int C) {
    int i = blockIdx.x * blockDim.x + threadIdx.x;
    if (i >= N * H) return;
    int n = i / H, hh = i - n * H;
    const float* hr = h + (size_t)n * H * C + hh * C;
    const float* as = a_src + hh * C;
    const float* ad = a_dst + hh * C;
    float ss = 0.0f, sd = 0.0f;
    for (int c = 0; c < C; ++c) {
        float v = hr[c];
        ss += v * as[c];
        sd += v * ad[c];
    }
    alpha_s[i] = ss;
    alpha_d[i] = sd;
}

// ---------------------------------------------------------------------------
// Aggregate: one wave per dst node. Two passes over CSR edges:
//   pass1: m = max leaky(alpha_s[src]+alpha_d[dst])   (per head)
//   pass2: p = exp(e-m); den += p; acc += p*h[src][col]; out = relu(acc/den+b)
// PL==1: lane -> (head=lane/C, c=lane%C)  [needs H*C==64]
// PL==2: lane covers (head=j, c=lane), j=0,1 [needs C==64,H==2]
// ---------------------------------------------------------------------------
template <int H, int C, int PL>
__global__ __launch_bounds__(256) void aggregate_kernel(
        const float* __restrict__ h,
        const float* __restrict__ alpha_s,
        const float* __restrict__ alpha_d,
        const int* __restrict__ row_ptr,
        const int* __restrict__ csr_src,
        const float* __restrict__ bias,
        float* __restrict__ out, int N) {
    constexpr int M = H * C;
    const int wid  = threadIdx.x >> 6;
    const int lane = threadIdx.x & 63;
    const int n = blockIdx.x * 4 + wid;
    if (n >= N) return;

    const int lo = row_ptr[n], hi = row_ptr[n + 1];

    int head[PL], col[PL];
    float adv[PL], mx[PL];
#pragma unroll
    for (int j = 0; j < PL; ++j) {
        head[j] = (PL == 1) ? (lane / C) : j;
        col[j]  = (PL == 1) ? lane : (j * C + lane);
        adv[j]  = alpha_d[n * H + head[j]];
        mx[j]   = -INFINITY;
    }

    for (int e = lo; e < hi; ++e) {
        int s = csr_src[e];
#pragma unroll
        for (int j = 0; j < PL; ++j) {
            float ev = alpha_s[s * H + head[j]] + adv[j];
            ev = ev > 0.0f ? ev : 0.2f * ev;
            mx[j] = fmaxf(mx[j], ev);
        }
    }

    float den[PL], acc[PL];
#pragma unroll
    for (int j = 0; j < PL; ++j) { den[j] = 0.0f; acc[j] = 0.0f; }

    for (int e = lo; e < hi; ++e) {
        int s = csr_src[e];
        const float* hr = h + (size_t)s * M;
#pragma unroll
        for (int j = 0; j < PL; ++j) {
            float ev = alpha_s[s * H + head[j]] + adv[j];
            ev = ev > 0.0f ? ev : 0.2f * ev;
            float p = __expf(ev - mx[j]);
            den[j] += p;
            acc[j] += p * hr[col[j]];
        }
    }

#pragma unroll
    for (int j = 0; j < PL; ++j) {
        float v = acc[j] / den[j] + bias[col[j]];
        out[(size_t)n * M + col[j]] = fmaxf(v, 0.0f);
    }
}

// ---------------------------------------------------------------------------

extern "C" void kernel_launch(void* const* d_in, const int* in_sizes, int n_in,
                              void* d_out, int out_size, void* d_ws, size_t ws_size,
                              hipStream_t stream) {
    const float* x   = (const float*)d_in[0];
    const int*   ei  = (const int*)  d_in[1];
    const float* w1  = (const float*)d_in[2];
    const float* as1 = (const float*)d_in[3];
    const float* ad1 = (const float*)d_in[4];
    const float* b1  = (const float*)d_in[5];
    const float* w2  = (const float*)d_in[6];
    const float* as2 = (const float*)d_in[7];
    const float* ad2 = (const float*)d_in[8];
    const float* b2  = (const float*)d_in[9];
    const float* w3  = (const float*)d_in[10];
    const float* as3 = (const float*)d_in[11];
    const float* ad3 = (const float*)d_in[12];
    const float* b3  = (const float*)d_in[13];
    const float* fcw = (const float*)d_in[14];
    const float* fcb = (const float*)d_in[15];
    float* out = (float*)d_out;

    const int N = in_sizes[0] / 128;
    const int E = in_sizes[1] / 2;
    const int Etot = E + N;

    // workspace carve-up (256B aligned regions)
    char* p = (char*)d_ws;
    auto alloc = [&](size_t bytes) {
        char* r = p;
        p += (bytes + 255) & ~(size_t)255;
        return r;
    };
    int*   cnt     = (int*)  alloc((size_t)N * 4);
    int*   row_ptr = (int*)  alloc((size_t)(N + 1) * 4);
    int*   cursor  = (int*)  alloc((size_t)N * 4);
    int*   csr_src = (int*)  alloc((size_t)Etot * 4);
    float* bufA    = (float*)alloc((size_t)N * 128 * 4);
    float* bufB    = (float*)alloc((size_t)N * 128 * 4);
    float* alpS    = (float*)alloc((size_t)N * 2 * 4);
    float* alpD    = (float*)alloc((size_t)N * 2 * 4);
    (void)ws_size; (void)n_in; (void)out_size;

    // ---- build CSR by dst ----
    hipMemsetAsync(cnt, 0, (size_t)N * 4, stream);
    int eb = (Etot + 255) / 256;
    count_kernel<<<eb, 256, 0, stream>>>(ei, E, N, cnt);
    scan_kernel<<<1, 1024, 0, stream>>>(cnt, N, Etot, row_ptr, cursor);
    scatter_kernel<<<eb, 256, 0, stream>>>(ei, E, N, cursor, csr_src);

    int ab = (N * 2 + 255) / 256;
    int gb = (N + 3) / 4;

    // ---- layer 1: 128 -> H2 x C32, concat ----
    gemm_kernel<128, 64><<<dim3(1024, 1), 256, 0, stream>>>(x, w1, nullptr, bufA, N, 64, 0);
    alpha_kernel<<<ab, 256, 0, stream>>>(bufA, as1, ad1, alpS, alpD, N, 2, 32);
    aggregate_kernel<2, 32, 1><<<gb, 256, 0, stream>>>(bufA, alpS, alpD, row_ptr, csr_src, b1, bufB, N);

    // ---- layer 2: 64 -> H2 x C64, concat ----
    gemm_kernel<64, 128><<<dim3(1024, 1), 256, 0, stream>>>(bufB, w2, nullptr, bufA, N, 128, 0);
    alpha_kernel<<<ab, 256, 0, stream>>>(bufA, as2, ad2, alpS, alpD, N, 2, 64);
    aggregate_kernel<2, 64, 2><<<gb, 256, 0, stream>>>(bufA, alpS, alpD, row_ptr, csr_src, b2, bufB, N);

    // ---- layer 3: 128 -> H1 x C64, mean (=identity for 1 head) ----
    gemm_kernel<128, 64><<<dim3(1024, 1), 256, 0, stream>>>(bufB, w3, nullptr, bufA, N, 64, 0);
    alpha_kernel<<<ab, 256, 0, stream>>>(bufA, as3, ad3, alpS, alpD, N, 1, 64);
    aggregate_kernel<1, 64, 1><<<gb, 256, 0, stream>>>(bufA, alpS, alpD, row_ptr, csr_src, b3, bufB, N);

    // ---- FC: 64 -> 512 + relu ----
    gemm_kernel<64, 128><<<dim3(1024, 4), 256, 0, stream>>>(bufB, fcw, fcb, out, N, 512, 1);
}

// Round 2
// 1108.354 us; speedup vs baseline: 1.3587x; 1.3587x over previous
//
#include <hip/hip_runtime.h>
#include <math.h>

// ---------------------------------------------------------------------------
// GAT pipeline: 3x (GEMM -> alpha -> CSR segment-softmax aggregate) + FC
// CSR built per launch (same work every call; graph-capture safe).
// R1: single-pass online-softmax aggregate w/ 4-edge unroll (MLP);
//     GEMM with 4-row blocking + ds_read_b128 weight layout.
// ---------------------------------------------------------------------------

__global__ void count_kernel(const int* __restrict__ ei, int E, int N,
                             int* __restrict__ cnt) {
    int e = blockIdx.x * blockDim.x + threadIdx.x;
    int Etot = E + N;
    if (e >= Etot) return;
    int dst = (e < E) ? ei[E + e] : (e - E);   // self-loops appended
    atomicAdd(&cnt[dst], 1);
}

__global__ __launch_bounds__(1024) void scan_kernel(const int* __restrict__ cnt,
                                                    int N, int Etot,
                                                    int* __restrict__ row_ptr,
                                                    int* __restrict__ cursor) {
    __shared__ int sums[1024];
    int tid = threadIdx.x;
    int chunk = (N + 1023) >> 10;
    int lo = tid * chunk;
    int hi = lo + chunk; if (hi > N) hi = N; if (lo > N) lo = N;
    int s = 0;
    for (int i = lo; i < hi; ++i) s += cnt[i];
    sums[tid] = s;
    __syncthreads();
    for (int off = 1; off < 1024; off <<= 1) {
        int t = (tid >= off) ? sums[tid - off] : 0;
        __syncthreads();
        sums[tid] += t;
        __syncthreads();
    }
    int run = sums[tid] - s;   // exclusive base for this thread's chunk
    for (int i = lo; i < hi; ++i) {
        row_ptr[i] = run;
        cursor[i]  = run;
        run += cnt[i];
    }
    if (tid == 0) row_ptr[N] = Etot;
}

__global__ void scatter_kernel(const int* __restrict__ ei, int E, int N,
                               int* __restrict__ cursor, int* __restrict__ csr_src) {
    int e = blockIdx.x * blockDim.x + threadIdx.x;
    int Etot = E + N;
    if (e >= Etot) return;
    int src, dst;
    if (e < E) { src = ei[e]; dst = ei[E + e]; }
    else       { src = e - E; dst = e - E; }
    int pos = atomicAdd(&cursor[dst], 1);
    csr_src[pos] = src;
}

// ---------------------------------------------------------------------------
// GEMM: out[n, cb+m] = sum_k in[n,k]*W[k,cb+m].  One wave handles RB
// consecutive rows (nodes); weights staged in LDS in [k/4][col][4] order so
// each lane pulls 4 k-values per column with one ds_read_b128.
// Per k4-iter: RB*PL*4 FMAs for PL b128 LDS reads (vs 1 FMA/b32 in R0).
// K*CHUNK <= 8192 (32 KB LDS).
// ---------------------------------------------------------------------------
template <int K, int CHUNK, int RB>
__global__ __launch_bounds__(256) void gemm_kernel(const float* __restrict__ in,
                                                   const float* __restrict__ W,
                                                   const float* __restrict__ bias,
                                                   float* __restrict__ out,
                                                   int N, int M, int relu) {
    constexpr int PL = CHUNK / 64;
    __shared__ float wlds[K * CHUNK];
    const int cb = blockIdx.y * CHUNK;
    for (int idx = threadIdx.x; idx < K * CHUNK; idx += 256) {
        int k = idx / CHUNK, c = idx % CHUNK;
        // layout: wlds4[k4][c] = {W[4k4+0][c], W[4k4+1][c], W[4k4+2][c], W[4k4+3][c]}
        wlds[(k >> 2) * (CHUNK * 4) + c * 4 + (k & 3)] = W[k * M + cb + c];
    }
    __syncthreads();

    const int wid  = threadIdx.x >> 6;
    const int lane = threadIdx.x & 63;
    const float4* wlds4 = (const float4*)wlds;

    const int n0 = (blockIdx.x * 4 + wid) * RB;
    if (n0 >= N) return;
    const bool full = (n0 + RB <= N);

    float b[PL];
#pragma unroll
    for (int j = 0; j < PL; ++j)
        b[j] = bias ? bias[cb + lane + 64 * j] : 0.0f;

    float acc[RB][PL];
#pragma unroll
    for (int r = 0; r < RB; ++r)
#pragma unroll
        for (int j = 0; j < PL; ++j) acc[r][j] = 0.0f;

    const float* xr = in + (size_t)n0 * K;

#pragma unroll 2
    for (int k4 = 0; k4 < K / 4; ++k4) {
        float4 xv[RB];
#pragma unroll
        for (int r = 0; r < RB; ++r) {
            if (full || n0 + r < N)
                xv[r] = ((const float4*)(xr + (size_t)r * K))[k4];
            else
                xv[r] = make_float4(0.f, 0.f, 0.f, 0.f);
        }
#pragma unroll
        for (int j = 0; j < PL; ++j) {
            float4 wv = wlds4[k4 * CHUNK + lane + 64 * j];
#pragma unroll
            for (int r = 0; r < RB; ++r) {
                acc[r][j] += xv[r].x * wv.x;
                acc[r][j] += xv[r].y * wv.y;
                acc[r][j] += xv[r].z * wv.z;
                acc[r][j] += xv[r].w * wv.w;
            }
        }
    }

#pragma unroll
    for (int r = 0; r < RB; ++r) {
        if (!full && n0 + r >= N) break;
#pragma unroll
        for (int j = 0; j < PL; ++j) {
            float v = acc[r][j] + b[j];
            if (relu) v = fmaxf(v, 0.0f);
            out[(size_t)(n0 + r) * M + cb + lane + 64 * j] = v;
        }
    }
}

// alpha_s[n,h] = sum_c h[n,h,c]*a_src[h,c]; alpha_d likewise. 1 thread/(n,h).
__global__ void alpha_kernel(const float* __restrict__ h,
                             const float* __restrict__ a_src,
                             const float* __restrict__ a_dst,
                             float* __restrict__ alpha_s,
                             float* __restrict__ alpha_d,
                             int N, int H, int C) {
    int i = blockIdx.x * blockDim.x + threadIdx.x;
    if (i >= N * H) return;
    int n = i / H, hh = i - n * H;
    const float* hr = h + (size_t)n * H * C + hh * C;
    const float* as = a_src + hh * C;
    const float* ad = a_dst + hh * C;
    float ss = 0.0f, sd = 0.0f;
    for (int c = 0; c < C; ++c) {
        float v = hr[c];
        ss += v * as[c];
        sd += v * ad[c];
    }
    alpha_s[i] = ss;
    alpha_d[i] = sd;
}

// ---------------------------------------------------------------------------
// Aggregate: one wave per dst node, SINGLE pass with online softmax.
// 4-edge manual unroll: all loads (csr_src, alpha_s, h) for 4 edges issued
// before the sequential online updates -> 8-16 outstanding gathers per wave.
// PL==1: lane -> (head=lane/C, c=lane%C)  [needs H*C==64]
// PL==2: lane covers (head=j, c=lane), j=0,1 [needs C==64,H==2]
// ---------------------------------------------------------------------------
template <int H, int C, int PL>
__global__ __launch_bounds__(256) void aggregate_kernel(
        const float* __restrict__ h,
        const float* __restrict__ alpha_s,
        const float* __restrict__ alpha_d,
        const int* __restrict__ row_ptr,
        const int* __restrict__ csr_src,
        const float* __restrict__ bias,
        float* __restrict__ out, int N) {
    constexpr int M = H * C;
    const int wid  = threadIdx.x >> 6;
    const int lane = threadIdx.x & 63;
    const int n = blockIdx.x * 4 + wid;
    if (n >= N) return;

    const int lo = row_ptr[n], hi = row_ptr[n + 1];

    int head[PL], col[PL];
    float adv[PL], mx[PL], den[PL], acc[PL];
#pragma unroll
    for (int j = 0; j < PL; ++j) {
        head[j] = (PL == 1) ? (lane / C) : j;
        col[j]  = (PL == 1) ? lane : (j * C + lane);
        adv[j]  = alpha_d[n * H + head[j]];
        mx[j]   = -INFINITY;
        den[j]  = 0.0f;
        acc[j]  = 0.0f;
    }

    int e = lo;
    for (; e + 4 <= hi; e += 4) {
        int s[4];
#pragma unroll
        for (int u = 0; u < 4; ++u) s[u] = csr_src[e + u];
        float ev[4][PL], hv[4][PL];
#pragma unroll
        for (int u = 0; u < 4; ++u)
#pragma unroll
            for (int j = 0; j < PL; ++j)
                ev[u][j] = alpha_s[s[u] * H + head[j]];
#pragma unroll
        for (int u = 0; u < 4; ++u)
#pragma unroll
            for (int j = 0; j < PL; ++j)
                hv[u][j] = h[(size_t)s[u] * M + col[j]];
#pragma unroll
        for (int u = 0; u < 4; ++u)
#pragma unroll
            for (int j = 0; j < PL; ++j) {
                float evv = ev[u][j] + adv[j];
                evv = evv > 0.0f ? evv : 0.2f * evv;
                float mnew = fmaxf(mx[j], evv);
                float sc = __expf(mx[j] - mnew);   // first edge: exp(-inf)=0
                float p  = __expf(evv - mnew);
                den[j] = den[j] * sc + p;
                acc[j] = acc[j] * sc + p * hv[u][j];
                mx[j]  = mnew;
            }
    }
    for (; e < hi; ++e) {
        int s = csr_src[e];
#pragma unroll
        for (int j = 0; j < PL; ++j) {
            float evv = alpha_s[s * H + head[j]] + adv[j];
            evv = evv > 0.0f ? evv : 0.2f * evv;
            float mnew = fmaxf(mx[j], evv);
            float sc = __expf(mx[j] - mnew);
            float p  = __expf(evv - mnew);
            den[j] = den[j] * sc + p;
            acc[j] = acc[j] * sc + p * h[(size_t)s * M + col[j]];
            mx[j]  = mnew;
        }
    }

#pragma unroll
    for (int j = 0; j < PL; ++j) {
        float v = acc[j] / den[j] + bias[col[j]];
        out[(size_t)n * M + col[j]] = fmaxf(v, 0.0f);
    }
}

// ---------------------------------------------------------------------------

extern "C" void kernel_launch(void* const* d_in, const int* in_sizes, int n_in,
                              void* d_out, int out_size, void* d_ws, size_t ws_size,
                              hipStream_t stream) {
    const float* x   = (const float*)d_in[0];
    const int*   ei  = (const int*)  d_in[1];
    const float* w1  = (const float*)d_in[2];
    const float* as1 = (const float*)d_in[3];
    const float* ad1 = (const float*)d_in[4];
    const float* b1  = (const float*)d_in[5];
    const float* w2  = (const float*)d_in[6];
    const float* as2 = (const float*)d_in[7];
    const float* ad2 = (const float*)d_in[8];
    const float* b2  = (const float*)d_in[9];
    const float* w3  = (const float*)d_in[10];
    const float* as3 = (const float*)d_in[11];
    const float* ad3 = (const float*)d_in[12];
    const float* b3  = (const float*)d_in[13];
    const float* fcw = (const float*)d_in[14];
    const float* fcb = (const float*)d_in[15];
    float* out = (float*)d_out;

    const int N = in_sizes[0] / 128;
    const int E = in_sizes[1] / 2;
    const int Etot = E + N;

    // workspace carve-up (256B aligned regions)
    char* p = (char*)d_ws;
    auto alloc = [&](size_t bytes) {
        char* r = p;
        p += (bytes + 255) & ~(size_t)255;
        return r;
    };
    int*   cnt     = (int*)  alloc((size_t)N * 4);
    int*   row_ptr = (int*)  alloc((size_t)(N + 1) * 4);
    int*   cursor  = (int*)  alloc((size_t)N * 4);
    int*   csr_src = (int*)  alloc((size_t)Etot * 4);
    float* bufA    = (float*)alloc((size_t)N * 128 * 4);
    float* bufB    = (float*)alloc((size_t)N * 128 * 4);
    float* alpS    = (float*)alloc((size_t)N * 2 * 4);
    float* alpD    = (float*)alloc((size_t)N * 2 * 4);
    (void)ws_size; (void)n_in; (void)out_size;

    // ---- build CSR by dst ----
    hipMemsetAsync(cnt, 0, (size_t)N * 4, stream);
    int eb = (Etot + 255) / 256;
    count_kernel<<<eb, 256, 0, stream>>>(ei, E, N, cnt);
    scan_kernel<<<1, 1024, 0, stream>>>(cnt, N, Etot, row_ptr, cursor);
    scatter_kernel<<<eb, 256, 0, stream>>>(ei, E, N, cursor, csr_src);

    int ab = (N * 2 + 255) / 256;
    int gb  = (N + 3) / 4;        // aggregate: 4 waves/block, 1 node/wave
    int gbr = (N + 15) / 16;      // gemm: 4 waves/block, RB=4 nodes/wave

    // ---- layer 1: 128 -> H2 x C32, concat ----
    gemm_kernel<128, 64, 4><<<dim3(gbr, 1), 256, 0, stream>>>(x, w1, nullptr, bufA, N, 64, 0);
    alpha_kernel<<<ab, 256, 0, stream>>>(bufA, as1, ad1, alpS, alpD, N, 2, 32);
    aggregate_kernel<2, 32, 1><<<gb, 256, 0, stream>>>(bufA, alpS, alpD, row_ptr, csr_src, b1, bufB, N);

    // ---- layer 2: 64 -> H2 x C64, concat ----
    gemm_kernel<64, 128, 4><<<dim3(gbr, 1), 256, 0, stream>>>(bufB, w2, nullptr, bufA, N, 128, 0);
    alpha_kernel<<<ab, 256, 0, stream>>>(bufA, as2, ad2, alpS, alpD, N, 2, 64);
    aggregate_kernel<2, 64, 2><<<gb, 256, 0, stream>>>(bufA, alpS, alpD, row_ptr, csr_src, b2, bufB, N);

    // ---- layer 3: 128 -> H1 x C64, mean (=identity for 1 head) ----
    gemm_kernel<128, 64, 4><<<dim3(gbr, 1), 256, 0, stream>>>(bufB, w3, nullptr, bufA, N, 64, 0);
    alpha_kernel<<<ab, 256, 0, stream>>>(bufA, as3, ad3, alpS, alpD, N, 1, 64);
    aggregate_kernel<1, 64, 1><<<gb, 256, 0, stream>>>(bufA, alpS, alpD, row_ptr, csr_src, b3, bufB, N);

    // ---- FC: 64 -> 512 + relu ----
    gemm_kernel<64, 128, 4><<<dim3(gbr, 4), 256, 0, stream>>>(bufB, fcw, fcb, out, N, 512, 1);
}